// Round 10
// baseline (876.552 us; speedup 1.0000x reference)
//
#include <hip/hip_runtime.h>
#include <hip/hip_cooperative_groups.h>
#include <hip/hip_bf16.h>
#include <math.h>

namespace cg = cooperative_groups;

// Problem dims: B=16,S=512,W=5,D=200,H=768  (BS=8192 rows, M1=40960 word-rows)
// Math: Ct = W2@attn_W^T; T = tanh(E@W1+b1); P = x@C; alpha = softmax(T_w.P+mask)
//       S = sum_w alpha_w T_w; H = x + S@W2 + b2 (bf16); out = LN(H)*gamma+beta
// R10: single cooperative megakernel (6 phases, grid.sync between) -- R9 audit:
//      kernel time sums ~110us vs dur 216us, so launch/overhead floor is first-
//      order; bank conflicts measured at only 4% of cycles (not worth fixing).
//      Also H stored bf16 (H-GEMM write + LN read: -37MB). Fallback to discrete
//      launches if hipLaunchCooperativeKernel errors (graph-capture safety).
//      Co-residency by construction: launch_bounds(256,4), 32KB LDS, grid 1024.

typedef __attribute__((ext_vector_type(8))) short bf16x8;
typedef __attribute__((ext_vector_type(4))) float f32x4;

__device__ __forceinline__ unsigned short f2bf_bits(float f) {
    __hip_bfloat16 h = __float2bfloat16(f);
    return *reinterpret_cast<unsigned short*>(&h);
}
__device__ __forceinline__ float bf_bits2f(unsigned short u) {
    union { unsigned int i; float f; } v; v.i = ((unsigned int)u) << 16; return v.f;
}
__device__ __forceinline__ float tanh_fast(float x) {
    float xc = fminf(fmaxf(x, -9.f), 9.f);
    float t  = __expf(2.f * xc);
    return (t - 1.f) * __builtin_amdgcn_rcpf(t + 1.f);
}
__device__ __forceinline__ void async_cp16(const void* g, void* lds) {
#if __has_builtin(__builtin_amdgcn_global_load_lds)
    auto gp = (const __attribute__((address_space(1))) unsigned int*)g;
    auto lp = (__attribute__((address_space(3))) unsigned int*)lds;
    __builtin_amdgcn_global_load_lds(gp, lp, 16, 0, 0);
#else
    *(uint4*)lds = *(const uint4*)g;
#endif
}

// ---------- MFMA bf16 GEMM body: D(bf16) = A@Bt^T (+bias)(tanh)(+resid) ----------
// XOR-swizzled LDS staging; BK=64; K%64==0; KREAL = valid k (zeros beyond).
// Safe for smem reuse across calls within one block (trailing barrier).
template<bool HAS_BIAS, bool TANH_ACT, bool RESID, int N, int K, int KREAL>
__device__ __forceinline__ void gemm_body(
    const __hip_bfloat16* __restrict__ A,
    const __hip_bfloat16* __restrict__ Bt,
    const float* __restrict__ bias,
    const float* __restrict__ resid,
    __hip_bfloat16* __restrict__ outp,
    int m0, int n0, unsigned char* smem)
{
    unsigned short* As = (unsigned short*)smem;            // 128x64 bf16 = 16KB
    unsigned short* Bs = (unsigned short*)(smem + 16384);  // 16KB

    const int tid  = threadIdx.x;
    const int lane = tid & 63;
    const int wave = tid >> 6;          // 4 waves, 2x2
    const int wm   = wave & 1;
    const int wn   = wave >> 1;

    const int rsub = lane >> 3;          // 0..7
    const int slot = lane & 7;           // 0..7
    const int kc   = slot ^ rsub;        // XOR swizzle: source permuted per lane
    const __hip_bfloat16* gA = A  + (size_t)(m0 + wave * 32 + rsub) * K + kc * 8;
    const __hip_bfloat16* gB = Bt + (size_t)(n0 + wave * 32 + rsub) * K + kc * 8;
    unsigned short* lA = As + wave * 2048 + lane * 8;
    unsigned short* lB = Bs + wave * 2048 + lane * 8;

    const int row16 = lane & 15;
    const int kq    = lane >> 4;         // 0..3

    f32x4 acc[4][4];
#pragma unroll
    for (int i = 0; i < 4; i++)
#pragma unroll
        for (int j = 0; j < 4; j++) acc[i][j] = (f32x4){0.f, 0.f, 0.f, 0.f};

#pragma unroll
    for (int k0 = 0; k0 < K; k0 += 64) {
#pragma unroll
        for (int i = 0; i < 4; i++) {
            async_cp16(gA + (size_t)(8 * i) * K, lA + i * 512);
            async_cp16(gB + (size_t)(8 * i) * K, lB + i * 512);
        }
        gA += 64; gB += 64;
        __syncthreads();

        const bool full = (k0 + 32 < KREAL);   // compile-time per unrolled iter

        bf16x8 af[2][4], bg[2][4];
#pragma unroll
        for (int mi = 0; mi < 4; mi++) {
            const int r = wm * 64 + mi * 16 + row16;
            af[0][mi] = *(const bf16x8*)&As[r * 64 + (kq ^ (r & 7)) * 8];
            if (full) af[1][mi] = *(const bf16x8*)&As[r * 64 + ((4 + kq) ^ (r & 7)) * 8];
        }
#pragma unroll
        for (int ni = 0; ni < 4; ni++) {
            const int r = wn * 64 + ni * 16 + row16;
            bg[0][ni] = *(const bf16x8*)&Bs[r * 64 + (kq ^ (r & 7)) * 8];
            if (full) bg[1][ni] = *(const bf16x8*)&Bs[r * 64 + ((4 + kq) ^ (r & 7)) * 8];
        }
#pragma unroll
        for (int mi = 0; mi < 4; mi++)
#pragma unroll
            for (int ni = 0; ni < 4; ni++)
                acc[mi][ni] = __builtin_amdgcn_mfma_f32_16x16x32_bf16(
                    af[0][mi], bg[0][ni], acc[mi][ni], 0, 0, 0);
        if (full) {
#pragma unroll
            for (int mi = 0; mi < 4; mi++)
#pragma unroll
                for (int ni = 0; ni < 4; ni++)
                    acc[mi][ni] = __builtin_amdgcn_mfma_f32_16x16x32_bf16(
                        af[1][mi], bg[1][ni], acc[mi][ni], 0, 0, 0);
        }
        __syncthreads();
    }

    // epilogue: repack through LDS, coalesced 16B stores; resid added fp32 in
    // the coalesced store phase.
    unsigned short* rep = (unsigned short*)smem;   // 128x128 bf16 = 32KB
#pragma unroll
    for (int ni = 0; ni < 4; ni++) {
        const int c = wn * 64 + ni * 16 + row16;
        float bcol = HAS_BIAS ? bias[n0 + c] : 0.f;
#pragma unroll
        for (int mi = 0; mi < 4; mi++)
#pragma unroll
            for (int r = 0; r < 4; r++) {
                const int rr = wm * 64 + mi * 16 + kq * 4 + r;
                float v = acc[mi][ni][r];
                if (HAS_BIAS) v += bcol;
                if (TANH_ACT) v = tanh_fast(v);
                rep[rr * 128 + c] = f2bf_bits(v);
            }
    }
    __syncthreads();
#pragma unroll
    for (int p = 0; p < 8; p++) {
        const int lin = p * 256 + tid;     // 128 rows x 16 chunks of 8
        const int row = lin >> 4;
        const int c8  = lin & 15;
        uint4 d = *(const uint4*)&rep[row * 128 + c8 * 8];
        if (RESID) {
            alignas(16) unsigned short us[8];
            *(uint4*)us = d;
            const float* rx = resid + (size_t)(m0 + row) * N + n0 + c8 * 8;
            float4 r0 = *(const float4*)rx;
            float4 r1 = *(const float4*)(rx + 4);
            us[0] = f2bf_bits(bf_bits2f(us[0]) + r0.x);
            us[1] = f2bf_bits(bf_bits2f(us[1]) + r0.y);
            us[2] = f2bf_bits(bf_bits2f(us[2]) + r0.z);
            us[3] = f2bf_bits(bf_bits2f(us[3]) + r0.w);
            us[4] = f2bf_bits(bf_bits2f(us[4]) + r1.x);
            us[5] = f2bf_bits(bf_bits2f(us[5]) + r1.y);
            us[6] = f2bf_bits(bf_bits2f(us[6]) + r1.z);
            us[7] = f2bf_bits(bf_bits2f(us[7]) + r1.w);
            d = *(const uint4*)us;
        }
        *(uint4*)(outp + (size_t)(m0 + row) * N + n0 + c8 * 8) = d;
    }
    __syncthreads();   // smem reused by the caller's next round
}

// ---------- phase unit functions ----------
__device__ __forceinline__ void prep_unit(
    int b, const float* __restrict__ x,  __hip_bfloat16* __restrict__ xb,
    const float* __restrict__ w2, __hip_bfloat16* __restrict__ w2b,
    const float* __restrict__ aw, __hip_bfloat16* __restrict__ awb,
    const float* __restrict__ E,  __hip_bfloat16* __restrict__ Eb,
    const float* __restrict__ W1, __hip_bfloat16* __restrict__ W1Tb,
    __hip_bfloat16* __restrict__ W2Tb, unsigned char* smem)
{
    const int tid = threadIdx.x;
    if (b < 6144 + 576 + 576) {                       // flat fp32->bf16 cvt
        const float* src; __hip_bfloat16* dst; long long i;
        if (b < 6144)      { src = x;  dst = xb;  i = (long long)b * 256 + tid; }
        else if (b < 6720) { src = w2; dst = w2b; i = (long long)(b - 6144) * 256 + tid; }
        else               { src = aw; dst = awb; i = (long long)(b - 6720) * 256 + tid; }
        float4 v = ((const float4*)src)[i];
        ((ushort4*)dst)[i] = make_ushort4(f2bf_bits(v.x), f2bf_bits(v.y), f2bf_bits(v.z), f2bf_bits(v.w));
    } else if (b < 7296 + 10240) {                    // E [40960,200] -> [40960,256]
        const int lane = tid & 63, wave = tid >> 6;
        const long long row = (long long)(b - 7296) * 4 + wave;
        const int k = lane * 4;
        float4 v = make_float4(0.f, 0.f, 0.f, 0.f);
        if (k < 200) v = *(const float4*)&E[row * 200 + k];   // k<=196 in-bounds
        *(ushort4*)&Eb[row * 256 + k] =
            make_ushort4(f2bf_bits(v.x), f2bf_bits(v.y), f2bf_bits(v.z), f2bf_bits(v.w));
    } else {                                          // transposes, (32,8) tiles
        float (*tile)[33] = (float(*)[33])smem;
        const float* in; __hip_bfloat16* outb; int R, C, Rpad, t;
        if (b < 17536 + 192) { t = b - 17536; in = W1; outb = W1Tb; R = 200; C = 768; Rpad = 256; }
        else                 { t = b - 17728; in = w2; outb = W2Tb; R = 768; C = 768; Rpad = 768; }
        const int c0 = (t % 24) * 32, r0 = (t / 24) * 32;
        const int xx = tid & 31, yy = tid >> 5;       // (32,8)
#pragma unroll
        for (int i = 0; i < 32; i += 8) {
            int r = r0 + yy + i;
            tile[yy + i][xx] = (r < R) ? in[(size_t)r * C + c0 + xx] : 0.f;
        }
        __syncthreads();
#pragma unroll
        for (int i = 0; i < 32; i += 8)
            outb[(size_t)(c0 + yy + i) * Rpad + r0 + xx] = __float2bfloat16(tile[xx][yy + i]);
        __syncthreads();   // tile reused next round
    }
}

__device__ __forceinline__ void tct_unit(
    int u, const __hip_bfloat16* Eb, const __hip_bfloat16* W1Tb, const float* b1,
    __hip_bfloat16* Tb, const __hip_bfloat16* W2b, const __hip_bfloat16* attnb,
    __hip_bfloat16* Ctb, unsigned char* smem)
{
    if (u < 1920) {
        gemm_body<true, true, false, 768, 256, 224>(
            Eb, W1Tb, b1, nullptr, Tb, (u / 6) * 128, (u % 6) * 128, smem);
    } else {
        const int id = u - 1920;    // 36 Ct tiles
        gemm_body<false, false, false, 768, 768, 768>(
            W2b, attnb, nullptr, nullptr, Ctb, (id / 6) * 128, (id % 6) * 128, smem);
    }
}

__device__ __forceinline__ void attn_unit(
    int u, const __hip_bfloat16* __restrict__ T, const __hip_bfloat16* P,
    const int* __restrict__ mask, __hip_bfloat16* S)
{
    const int lane = threadIdx.x & 63;
    const int wave = threadIdx.x >> 6;
    const int r    = u * 4 + wave;
    const int base = lane * 12;

    float pv[12];
    {
        const ushort4* pp = (const ushort4*)((const unsigned short*)P + (size_t)r * 768 + base);
        ushort4 u0 = pp[0], u1 = pp[1], u2 = pp[2];
        unsigned short us[12] = {u0.x,u0.y,u0.z,u0.w, u1.x,u1.y,u1.z,u1.w, u2.x,u2.y,u2.z,u2.w};
#pragma unroll
        for (int j = 0; j < 12; j++) pv[j] = bf_bits2f(us[j]);
    }
    float tv[5][12], part[5];
#pragma unroll
    for (int w = 0; w < 5; w++) {
        const ushort4* tp = (const ushort4*)((const unsigned short*)T + ((size_t)r * 5 + w) * 768 + base);
        ushort4 u0 = tp[0], u1 = tp[1], u2 = tp[2];
        unsigned short us[12] = {u0.x,u0.y,u0.z,u0.w, u1.x,u1.y,u1.z,u1.w, u2.x,u2.y,u2.z,u2.w};
        float s = 0.f;
#pragma unroll
        for (int j = 0; j < 12; j++) { tv[w][j] = bf_bits2f(us[j]); s += tv[w][j] * pv[j]; }
        part[w] = s;
    }
#pragma unroll
    for (int off = 32; off > 0; off >>= 1)
#pragma unroll
        for (int w = 0; w < 5; w++)
            part[w] += __shfl_xor(part[w], off, 64);

    float logit[5], mx = -1e30f;
#pragma unroll
    for (int w = 0; w < 5; w++) {
        float m = (float)mask[(size_t)r * 5 + w];
        logit[w] = part[w] - 10000.0f * (1.0f - m);
        mx = fmaxf(mx, logit[w]);
    }
    float se = 0.f;
#pragma unroll
    for (int w = 0; w < 5; w++) { logit[w] = expf(logit[w] - mx); se += logit[w]; }
    const float inv = 1.0f / se;

    unsigned short os[12];
#pragma unroll
    for (int j = 0; j < 12; j++) {
        float s = 0.f;
#pragma unroll
        for (int w = 0; w < 5; w++) s += logit[w] * tv[w][j];
        os[j] = f2bf_bits(s * inv);
    }
    ushort4* sp = (ushort4*)((unsigned short*)S + (size_t)r * 768 + base);
    sp[0] = make_ushort4(os[0], os[1], os[2],  os[3]);
    sp[1] = make_ushort4(os[4], os[5], os[6],  os[7]);
    sp[2] = make_ushort4(os[8], os[9], os[10], os[11]);
}

__device__ __forceinline__ void ln_unit(
    int u, const __hip_bfloat16* __restrict__ Hb, const float* __restrict__ gamma,
    const float* __restrict__ beta, float* __restrict__ out)
{
    const int lane = threadIdx.x & 63;
    const int wave = threadIdx.x >> 6;
    const int r    = u * 4 + wave;
    const unsigned short* hr = (const unsigned short*)Hb + (size_t)r * 768 + lane * 12;

    float v[12];
    {
        ushort4 a = ((const ushort4*)hr)[0], b4 = ((const ushort4*)hr)[1], c4 = ((const ushort4*)hr)[2];
        v[0]=bf_bits2f(a.x);  v[1]=bf_bits2f(a.y);  v[2]=bf_bits2f(a.z);  v[3]=bf_bits2f(a.w);
        v[4]=bf_bits2f(b4.x); v[5]=bf_bits2f(b4.y); v[6]=bf_bits2f(b4.z); v[7]=bf_bits2f(b4.w);
        v[8]=bf_bits2f(c4.x); v[9]=bf_bits2f(c4.y); v[10]=bf_bits2f(c4.z); v[11]=bf_bits2f(c4.w);
    }
    float s = 0.f;
#pragma unroll
    for (int j = 0; j < 12; j++) s += v[j];
#pragma unroll
    for (int off = 32; off > 0; off >>= 1) s += __shfl_xor(s, off, 64);
    const float mu = s * (1.f / 768.f);
    float vs = 0.f;
#pragma unroll
    for (int j = 0; j < 12; j++) { float d = v[j] - mu; vs += d * d; }
#pragma unroll
    for (int off = 32; off > 0; off >>= 1) vs += __shfl_xor(vs, off, 64);
    const float rs = rsqrtf(vs * (1.f / 768.f) + 1e-12f);

    float o[12];
#pragma unroll
    for (int j = 0; j < 12; j++) {
        int h = lane * 12 + j;
        o[j] = (v[j] - mu) * rs * gamma[h] + beta[h];
    }
    float* orow = out + (size_t)r * 768 + lane * 12;
    *(float4*)(orow)     = make_float4(o[0], o[1], o[2],  o[3]);
    *(float4*)(orow + 4) = make_float4(o[4], o[5], o[6],  o[7]);
    *(float4*)(orow + 8) = make_float4(o[8], o[9], o[10], o[11]);
}

// ---------- cooperative megakernel: all 6 phases, grid.sync between ----------
__global__ __launch_bounds__(256, 4) void mega_kernel(
    const float* x, const float* E, const int* mask,
    const float* W1, const float* b1, const float* W2, const float* b2,
    const float* attn_W, const float* gamma, const float* beta, float* out,
    __hip_bfloat16* xb, __hip_bfloat16* W2b, __hip_bfloat16* W2Tb,
    __hip_bfloat16* attnb, __hip_bfloat16* Ctb, __hip_bfloat16* W1Tb,
    __hip_bfloat16* Tb, __hip_bfloat16* Eb)
{
    __shared__ __align__(16) unsigned char smem[32768];
    cg::grid_group grid = cg::this_grid();
    const int G = gridDim.x;

    for (int b = blockIdx.x; b < 18304; b += G)
        prep_unit(b, x, xb, W2, W2b, attn_W, attnb, E, Eb, W1, W1Tb, W2Tb, smem);
    grid.sync();
    for (int u = blockIdx.x; u < 1956; u += G)
        tct_unit(u, Eb, W1Tb, b1, Tb, W2b, attnb, Ctb, smem);
    grid.sync();
    for (int u = blockIdx.x; u < 384; u += G)   // P = x@C -> Eb region
        gemm_body<false, false, false, 768, 768, 768>(
            xb, Ctb, nullptr, nullptr, Eb, (u / 6) * 128, (u % 6) * 128, smem);
    grid.sync();
    for (int u = blockIdx.x; u < 2048; u += G)  // attn: P(=Eb) -> S(=Eb)
        attn_unit(u, Tb, Eb, mask, Eb);
    grid.sync();
    for (int u = blockIdx.x; u < 384; u += G)   // H = x + S@W2 + b2 (bf16) -> Tb
        gemm_body<true, false, true, 768, 768, 768>(
            Eb, W2Tb, b2, x, Tb, (u / 6) * 128, (u % 6) * 128, smem);
    grid.sync();
    for (int u = blockIdx.x; u < 2048; u += G)  // LN(Tb) -> out
        ln_unit(u, Tb, gamma, beta, out);
}

// ---------- fallback wrappers (non-cooperative) ----------
__global__ __launch_bounds__(256) void k_prep(
    const float* x, __hip_bfloat16* xb, const float* w2, __hip_bfloat16* w2b,
    const float* aw, __hip_bfloat16* awb, const float* E, __hip_bfloat16* Eb,
    const float* W1, __hip_bfloat16* W1Tb, __hip_bfloat16* W2Tb)
{
    __shared__ __align__(16) unsigned char smem[4224];
    prep_unit(blockIdx.x, x, xb, w2, w2b, aw, awb, E, Eb, W1, W1Tb, W2Tb, smem);
}
__global__ __launch_bounds__(256) void k_tct(
    const __hip_bfloat16* Eb, const __hip_bfloat16* W1Tb, const float* b1,
    __hip_bfloat16* Tb, const __hip_bfloat16* W2b, const __hip_bfloat16* attnb,
    __hip_bfloat16* Ctb)
{
    __shared__ __align__(16) unsigned char smem[32768];
    tct_unit(blockIdx.x, Eb, W1Tb, b1, Tb, W2b, attnb, Ctb, smem);
}
__global__ __launch_bounds__(256) void k_pgemm(
    const __hip_bfloat16* xb, const __hip_bfloat16* Ctb, __hip_bfloat16* Pb)
{
    __shared__ __align__(16) unsigned char smem[32768];
    gemm_body<false, false, false, 768, 768, 768>(
        xb, Ctb, nullptr, nullptr, Pb, (blockIdx.x / 6) * 128, (blockIdx.x % 6) * 128, smem);
}
__global__ __launch_bounds__(256) void k_attn(
    const __hip_bfloat16* T, const __hip_bfloat16* P, const int* mask, __hip_bfloat16* S)
{
    attn_unit(blockIdx.x, T, P, mask, S);
}
__global__ __launch_bounds__(256) void k_hgemm(
    const __hip_bfloat16* Sb, const __hip_bfloat16* W2Tb, const float* b2,
    const float* x, __hip_bfloat16* Hb)
{
    __shared__ __align__(16) unsigned char smem[32768];
    gemm_body<true, false, true, 768, 768, 768>(
        Sb, W2Tb, b2, x, Hb, (blockIdx.x / 6) * 128, (blockIdx.x % 6) * 128, smem);
}
__global__ __launch_bounds__(256) void k_ln(
    const __hip_bfloat16* Hb, const float* gamma, const float* beta, float* out)
{
    ln_unit(blockIdx.x, Hb, gamma, beta, out);
}

extern "C" void kernel_launch(void* const* d_in, const int* in_sizes, int n_in,
                              void* d_out, int out_size, void* d_ws, size_t ws_size,
                              hipStream_t stream)
{
    const float* x      = (const float*)d_in[0];
    const float* E      = (const float*)d_in[1];
    const int*   mask   = (const int*)d_in[2];
    const float* W1     = (const float*)d_in[3];
    const float* b1     = (const float*)d_in[4];
    const float* W2     = (const float*)d_in[5];
    const float* b2     = (const float*)d_in[6];
    const float* attn_W = (const float*)d_in[7];
    const float* gamma  = (const float*)d_in[8];
    const float* beta   = (const float*)d_in[9];
    float* out = (float*)d_out;

    const int BS = 8192, H = 768, M1 = 40960, KP = 256;

    char* p = (char*)d_ws;
    auto alloc = [&](size_t bytes) { char* q = p; p += (bytes + 255) & ~(size_t)255; return q; };
    __hip_bfloat16* xb    = (__hip_bfloat16*)alloc((size_t)BS * H * 2);    // 12.58 MB
    __hip_bfloat16* W2b   = (__hip_bfloat16*)alloc((size_t)H * H * 2);
    __hip_bfloat16* W2Tb  = (__hip_bfloat16*)alloc((size_t)H * H * 2);
    __hip_bfloat16* attnb = (__hip_bfloat16*)alloc((size_t)H * H * 2);
    __hip_bfloat16* Ctb   = (__hip_bfloat16*)alloc((size_t)H * H * 2);
    __hip_bfloat16* W1Tb  = (__hip_bfloat16*)alloc((size_t)H * KP * 2);
    __hip_bfloat16* Tb    = (__hip_bfloat16*)alloc((size_t)M1 * H * 2);    // 62.92 MB
    __hip_bfloat16* Eb    = (__hip_bfloat16*)alloc((size_t)M1 * KP * 2);   // 20.97 MB
    // aliases: P/S live in Eb (dead after tct); H(bf16) lives in Tb (dead after attn)

    void* kargs[] = {
        (void*)&x, (void*)&E, (void*)&mask, (void*)&W1, (void*)&b1, (void*)&W2,
        (void*)&b2, (void*)&attn_W, (void*)&gamma, (void*)&beta, (void*)&out,
        (void*)&xb, (void*)&W2b, (void*)&W2Tb, (void*)&attnb, (void*)&Ctb,
        (void*)&W1Tb, (void*)&Tb, (void*)&Eb };

    hipError_t err = hipLaunchCooperativeKernel(
        (const void*)mega_kernel, dim3(1024), dim3(256), kargs, 0, stream);
    if (err != hipSuccess) {
        (void)hipGetLastError();   // clear sticky error, fall back to discrete launches
        k_prep <<<18304, 256, 0, stream>>>(x, xb, W2, W2b, attn_W, attnb, E, Eb, W1, W1Tb, W2Tb);
        k_tct  <<<1956,  256, 0, stream>>>(Eb, W1Tb, b1, Tb, W2b, attnb, Ctb);
        k_pgemm<<<384,   256, 0, stream>>>(xb, Ctb, Eb);
        k_attn <<<2048,  256, 0, stream>>>(Tb, Eb, mask, Eb);
        k_hgemm<<<384,   256, 0, stream>>>(Eb, W2Tb, b2, x, Tb);
        k_ln   <<<2048,  256, 0, stream>>>(Tb, gamma, beta, out);
    }
}